// Round 1
// baseline (1449.919 us; speedup 1.0000x reference)
//
#include <hip/hip_runtime.h>
#include <math.h>

#define B_ 2
#define N_ 16384
#define D_ 512
#define H_ 256
#define C_ 4
#define K_ 8
#define ROWS (B_*N_)   // 32768
#define EPS_ 1e-12f

// ---------------- K0: per-row inverse L2 norm of x ----------------
__global__ __launch_bounds__(256) void rownorm_kernel(const float* __restrict__ x,
                                                      float* __restrict__ invn) {
    int wave = threadIdx.x >> 6;
    int lane = threadIdx.x & 63;
    int row  = blockIdx.x * 4 + wave;
    const float* xr = x + (size_t)row * D_;
    float s = 0.f;
    for (int j = 0; j < D_; j += 64) { float v = xr[j + lane]; s += v * v; }
    for (int off = 32; off; off >>= 1) s += __shfl_down(s, off, 64);
    if (lane == 0) invn[row] = 1.0f / fmaxf(sqrtf(s), EPS_);
}

// ---------------- K1: tiled fp32 GEMM  C[m][coff+n] = (A[m]*asc[m]) . B[:,n] + bias[n]
// A: [M x 512] lda=512 ; B: [512 x ldb] ; tile 64x64, BK=16, 4x4 per thread.
__global__ __launch_bounds__(256) void gemm_kernel(
    const float* __restrict__ A, const float* __restrict__ ascale,
    const float* __restrict__ Bm, const float* __restrict__ bias,
    float* __restrict__ Cm, int ldb, int ldc, int coff)
{
    __shared__ float As[16 * 65];
    __shared__ float Bs[16 * 64];
    int t  = threadIdx.x;
    int m0 = blockIdx.y * 64;
    int n0 = blockIdx.x * 64;
    int tx = t & 15, ty = t >> 4;
    float acc[4][4] = {};

    int arow = t >> 2;          // 0..63
    int akc  = (t & 3) * 4;     // 0,4,8,12
    int brow = t >> 4;          // 0..15
    int bcol = (t & 15) * 4;    // 0..60
    float asc = ascale ? ascale[m0 + arow] : 1.0f;
    const float* Aptr = A + (size_t)(m0 + arow) * D_ + akc;
    const float* Bptr = Bm + (size_t)brow * ldb + n0 + bcol;

    for (int k0 = 0; k0 < D_; k0 += 16) {
        float4 av = *(const float4*)(Aptr + k0);
        float4 bv = *(const float4*)(Bptr + (size_t)k0 * ldb);
        As[(akc + 0) * 65 + arow] = av.x * asc;
        As[(akc + 1) * 65 + arow] = av.y * asc;
        As[(akc + 2) * 65 + arow] = av.z * asc;
        As[(akc + 3) * 65 + arow] = av.w * asc;
        *(float4*)&Bs[brow * 64 + bcol] = bv;
        __syncthreads();
#pragma unroll
        for (int kk = 0; kk < 16; ++kk) {
            float a[4], b[4];
#pragma unroll
            for (int i = 0; i < 4; ++i) a[i] = As[kk * 65 + ty * 4 + i];
#pragma unroll
            for (int j = 0; j < 4; ++j) b[j] = Bs[kk * 64 + tx * 4 + j];
#pragma unroll
            for (int i = 0; i < 4; ++i)
#pragma unroll
                for (int j = 0; j < 4; ++j) acc[i][j] += a[i] * b[j];
        }
        __syncthreads();
    }
#pragma unroll
    for (int i = 0; i < 4; ++i) {
        int gm = m0 + ty * 4 + i;
        float4 o;
        int gn = n0 + tx * 4;
        o.x = acc[i][0] + (bias ? bias[gn + 0] : 0.f);
        o.y = acc[i][1] + (bias ? bias[gn + 1] : 0.f);
        o.z = acc[i][2] + (bias ? bias[gn + 2] : 0.f);
        o.w = acc[i][3] + (bias ? bias[gn + 3] : 0.f);
        *(float4*)&Cm[(size_t)gm * ldc + coff + gn] = o;
    }
}

// ---------------- K2: in-place row l2norm of xp + class scores ----------------
__global__ __launch_bounds__(256) void normclass_kernel(
    float* __restrict__ xp, const float* __restrict__ desc, float* __restrict__ cls_out)
{
    __shared__ float sx[512];
    __shared__ float sred[8];
    __shared__ float sdots[32];
    int t = threadIdx.x;
    size_t row = blockIdx.x;
    float* xr = xp + row * D_;
    float v0 = xr[t], v1 = xr[t + 256];
    float p = v0 * v0 + v1 * v1;
    int lane = t & 63, wave = t >> 6;
    for (int off = 32; off; off >>= 1) p += __shfl_down(p, off, 64);
    if (lane == 0) sred[wave] = p;
    __syncthreads();
    if (t == 0) {
        float s = sred[0] + sred[1] + sred[2] + sred[3];
        sred[4] = 1.0f / fmaxf(sqrtf(s), EPS_);
    }
    __syncthreads();
    float inv = sred[4];
    v0 *= inv; v1 *= inv;
    sx[t] = v0; sx[t + 256] = v1;
    xr[t] = v0; xr[t + 256] = v1;
    __syncthreads();
    // 32 (c,k) dot products; wave w handles pairs w*8..w*8+7
    for (int q = 0; q < 8; ++q) {
        int pidx = wave * 8 + q;
        const float* dp = desc + (size_t)pidx * D_;
        float s = 0.f;
        for (int j = 0; j < D_; j += 64) s += sx[j + lane] * dp[j + lane];
        for (int off = 32; off; off >>= 1) s += __shfl_down(s, off, 64);
        if (lane == 0) sdots[pidx] = s;
    }
    __syncthreads();
    if (t < C_) {
        const float scale = 0.04419417382415922f;  // 512^-0.5
        float m = -1e30f;
        for (int k = 0; k < K_; ++k) m = fmaxf(m, sdots[t * K_ + k] * scale);
        float den = 0.f, num = 0.f;
        for (int k = 0; k < K_; ++k) {
            float e = expf(sdots[t * K_ + k] * scale - m);
            den += e; num += e * sdots[t * K_ + k];
        }
        cls_out[row * C_ + t] = num / den;
    }
}

// ---------------- K4: gated attention scalar per row ----------------
__global__ __launch_bounds__(256) void gatedA_kernel(
    const float* __restrict__ hvu, const float* __restrict__ w_attn,
    const float* __restrict__ b_attn, float* __restrict__ Araw)
{
    int wave = threadIdx.x >> 6, lane = threadIdx.x & 63;
    size_t row = (size_t)blockIdx.x * 4 + wave;
    const float* hr = hvu + row * 512;
    float s = 0.f;
    for (int j = 0; j < 256; j += 64) {
        int h = j + lane;
        float gv = tanhf(hr[h]);
        float gu = 1.0f / (1.0f + expf(-hr[256 + h]));
        s += gv * gu * w_attn[h];
    }
    for (int off = 32; off; off >>= 1) s += __shfl_down(s, off, 64);
    if (lane == 0) Araw[row] = s + b_attn[0];
}

// ---------------- K5: softmax over N per batch ----------------
__global__ __launch_bounds__(256) void softmaxN_kernel(float* __restrict__ A)
{
    __shared__ float red[256];
    int t = threadIdx.x;
    float* Ab = A + (size_t)blockIdx.x * N_;
    float m = -1e30f;
    for (int i = t; i < N_; i += 256) m = fmaxf(m, Ab[i]);
    red[t] = m; __syncthreads();
    for (int s = 128; s; s >>= 1) { if (t < s) red[t] = fmaxf(red[t], red[t + s]); __syncthreads(); }
    m = red[0]; __syncthreads();
    float sum = 0.f;
    for (int i = t; i < N_; i += 256) { float e = expf(Ab[i] - m); Ab[i] = e; sum += e; }
    red[t] = sum; __syncthreads();
    for (int s = 128; s; s >>= 1) { if (t < s) red[t] += red[t + s]; __syncthreads(); }
    float inv = 1.0f / red[0];
    for (int i = t; i < N_; i += 256) Ab[i] *= inv;
}

// ---------------- K6: weighted pooling  slide[b] += sum A[n]*xp[n] ----------------
__global__ __launch_bounds__(256) void pool_kernel(
    const float* __restrict__ A, const float* __restrict__ xp, float* __restrict__ slide)
{
    int b = blockIdx.y;
    int t = threadIdx.x;
    size_t base = (size_t)b * N_ + (size_t)blockIdx.x * 64;
    float a0 = 0.f, a1 = 0.f;
    for (int r = 0; r < 64; ++r) {
        size_t row = base + r;
        float a = A[row];
        const float* xr = xp + row * D_;
        a0 += a * xr[t];
        a1 += a * xr[t + 256];
    }
    atomicAdd(&slide[b * D_ + t], a0);
    atomicAdd(&slide[b * D_ + t + 256], a1);
}

// ---------------- K7: finalize — text feats, slide norms, logits, softmax, argmax
__global__ __launch_bounds__(512) void finalize_kernel(
    const float* __restrict__ slide_s, const float* __restrict__ slide_l,
    const float* __restrict__ desc, float* __restrict__ out)
{
    __shared__ float txt[4][512];
    __shared__ float ssn[2][512];
    __shared__ float sln[2][512];
    __shared__ float red[512];
    __shared__ float lg[8];
    int t = threadIdx.x;

    auto reduceSum = [&](float v) -> float {
        red[t] = v; __syncthreads();
        for (int s = 256; s; s >>= 1) { if (t < s) red[t] += red[t + s]; __syncthreads(); }
        float r = red[0]; __syncthreads();
        return r;
    };

    for (int c = 0; c < 4; ++c) {
        float m = -1e30f;
        for (int k = 0; k < 8; ++k) m = fmaxf(m, desc[((size_t)c * 8 + k) * 512 + t]);
        float ss = reduceSum(m * m);
        txt[c][t] = m / fmaxf(sqrtf(ss), EPS_);
    }
    for (int b = 0; b < 2; ++b) {
        float v = slide_s[b * 512 + t];
        float ss = reduceSum(v * v);
        ssn[b][t] = v / fmaxf(sqrtf(ss), EPS_);
        v = slide_l[b * 512 + t];
        ss = reduceSum(v * v);
        sln[b][t] = v / fmaxf(sqrtf(ss), EPS_);
    }
    __syncthreads();
    for (int b = 0; b < 2; ++b)
        for (int c = 0; c < 4; ++c) {
            float v = ssn[b][t] * txt[c][t] + sln[b][t] * txt[c][t];
            float s = reduceSum(v);
            if (t == 0) lg[b * 4 + c] = s;
        }
    __syncthreads();
    if (t < 2) {
        int b = t;
        float m = -1e30f;
        for (int c = 0; c < 4; ++c) m = fmaxf(m, lg[b * 4 + c]);
        float e[4]; float den = 0.f;
        for (int c = 0; c < 4; ++c) { e[c] = expf(lg[b * 4 + c] - m); den += e[c]; }
        int am = 0; float bm = -1.f;
        for (int c = 0; c < 4; ++c) {
            float pcl = e[c] / den;
            out[b * 4 + c] = pcl;
            if (pcl > bm) { bm = pcl; am = c; }
        }
        out[8 + b] = (float)am;
    }
}

extern "C" void kernel_launch(void* const* d_in, const int* in_sizes, int n_in,
                              void* d_out, int out_size, void* d_ws, size_t ws_size,
                              hipStream_t stream) {
    const float* x_s    = (const float*)d_in[0];
    const float* x_l    = (const float*)d_in[2];
    const float* W_proj = (const float*)d_in[4];
    const float* b_proj = (const float*)d_in[5];
    const float* desc   = (const float*)d_in[6];
    const float* Wv     = (const float*)d_in[7];
    const float* bv     = (const float*)d_in[8];
    const float* Wu     = (const float*)d_in[9];
    const float* bu     = (const float*)d_in[10];
    const float* w_attn = (const float*)d_in[11];
    const float* b_attn = (const float*)d_in[12];
    float* out = (float*)d_out;

    // workspace layout (floats): xp[32768*512] | hvu[32768*512] | Araw[32768] |
    //                            invn[32768] | slide_s[1024] | slide_l[1024]
    float* ws      = (float*)d_ws;
    float* xp      = ws;
    float* hvu     = ws + (size_t)ROWS * D_;
    float* Araw    = hvu + (size_t)ROWS * D_;
    float* invn    = Araw + ROWS;
    float* slide_s = invn + ROWS;
    float* slide_l = slide_s + 1024;

    hipMemsetAsync(slide_s, 0, 2048 * sizeof(float), stream);

    float* cls_s = out + 10;
    float* cls_l = out + 10 + (size_t)ROWS * C_;

    for (int s = 0; s < 2; ++s) {
        const float* x = s ? x_l : x_s;
        float* cls     = s ? cls_l : cls_s;
        float* slide   = s ? slide_l : slide_s;

        rownorm_kernel<<<ROWS / 4, 256, 0, stream>>>(x, invn);
        gemm_kernel<<<dim3(8, ROWS / 64), 256, 0, stream>>>(x, invn, W_proj, b_proj, xp, 512, 512, 0);
        normclass_kernel<<<ROWS, 256, 0, stream>>>(xp, desc, cls);
        gemm_kernel<<<dim3(4, ROWS / 64), 256, 0, stream>>>(xp, nullptr, Wv, bv, hvu, 256, 512, 0);
        gemm_kernel<<<dim3(4, ROWS / 64), 256, 0, stream>>>(xp, nullptr, Wu, bu, hvu, 256, 512, 256);
        gatedA_kernel<<<ROWS / 4, 256, 0, stream>>>(hvu, w_attn, b_attn, Araw);
        softmaxN_kernel<<<2, 256, 0, stream>>>(Araw);
        pool_kernel<<<dim3(N_ / 64, 2), 256, 0, stream>>>(Araw, xp, slide);
    }
    finalize_kernel<<<1, 512, 0, stream>>>(slide_s, slide_l, desc, out);
}

// Round 2
// 688.388 us; speedup vs baseline: 2.1063x; 2.1063x over previous
//
#include <hip/hip_runtime.h>
#include <math.h>

#define B_ 2
#define N_ 16384
#define D_ 512
#define C_ 4
#define K_ 8
#define ROWS (B_*N_)   // 32768
#define EPS_ 1e-12f

typedef unsigned short u16;
typedef unsigned int u32;
using short8  = __attribute__((ext_vector_type(8))) short;
using float4v = __attribute__((ext_vector_type(4))) float;

__device__ __forceinline__ u16 f2bf(float f) {
    union { float f; u32 u; } v; v.f = f;
    u32 r = v.u + 0x7fffu + ((v.u >> 16) & 1u);
    return (u16)(r >> 16);
}
__device__ __forceinline__ float bf2f(u16 h) {
    union { u32 u; float f; } v; v.u = ((u32)h) << 16;
    return v.f;
}
__device__ __forceinline__ void load_lds16(const u16* g, u16* l) {
    __builtin_amdgcn_global_load_lds(
        (const __attribute__((address_space(1))) u32*)g,
        (__attribute__((address_space(3))) u32*)l, 16, 0, 0);
}

// ---------------- P0: weight transpose + bf16 cast + bias concat ----------------
__global__ __launch_bounds__(256) void prep_weights_kernel(
    const float* __restrict__ Wp, const float* __restrict__ Wv, const float* __restrict__ Wu,
    const float* __restrict__ bv, const float* __restrict__ bu,
    u16* __restrict__ WpT, u16* __restrict__ WvuT, float* __restrict__ bvu)
{
    int idx = blockIdx.x * 256 + threadIdx.x;   // 0 .. 512*512-1
    int n = idx >> 9, k = idx & 511;
    WpT[idx] = f2bf(Wp[k * 512 + n]);
    float v = (n < 256) ? Wv[k * 256 + n] : Wu[k * 256 + (n - 256)];
    WvuT[idx] = f2bf(v);
    if (idx < 512) bvu[idx] = (idx < 256) ? bv[idx] : bu[idx - 256];
}

// ---------------- K0: per-row L2-normalize x and cast to bf16 ----------------
__global__ __launch_bounds__(256) void rownorm_cast_kernel(
    const float* __restrict__ x, u16* __restrict__ xn)
{
    int wave = threadIdx.x >> 6, lane = threadIdx.x & 63;
    size_t row = (size_t)blockIdx.x * 4 + wave;
    const float* xr = x + row * D_;
    float4 a = *(const float4*)&xr[lane * 8];
    float4 b = *(const float4*)&xr[lane * 8 + 4];
    float s = a.x*a.x + a.y*a.y + a.z*a.z + a.w*a.w
            + b.x*b.x + b.y*b.y + b.z*b.z + b.w*b.w;
#pragma unroll
    for (int off = 32; off; off >>= 1) s += __shfl_xor(s, off, 64);
    float inv = 1.0f / fmaxf(sqrtf(s), EPS_);
    uint4 o;
    o.x = (u32)f2bf(a.x * inv) | ((u32)f2bf(a.y * inv) << 16);
    o.y = (u32)f2bf(a.z * inv) | ((u32)f2bf(a.w * inv) << 16);
    o.z = (u32)f2bf(b.x * inv) | ((u32)f2bf(b.y * inv) << 16);
    o.w = (u32)f2bf(b.z * inv) | ((u32)f2bf(b.w * inv) << 16);
    *(uint4*)&xn[row * D_ + lane * 8] = o;
}

// ---------------- K1: bf16 MFMA GEMM  C[M,512] = A[M,512] @ Bt[512,512]^T + bias
// 128x128 tile, BK=32, 4 waves each 64x64 (4x4 MFMA 16x16x32).
// A, Bt staged into LDS in MFMA *fragment order* via global_load_lds(16B):
//   subtile (16 rows x 32 k) occupies 1KB; lane i carries row (i&15), k-chunk (i>>4).
__global__ __launch_bounds__(256) void gemm_bf16_kernel(
    const u16* __restrict__ A, const u16* __restrict__ Bt,
    const float* __restrict__ bias, u16* __restrict__ C)
{
    __shared__ u16 ldsA[8 * 512];
    __shared__ u16 ldsB[8 * 512];
    int t = threadIdx.x;
    int wave = t >> 6, lane = t & 63;
    int M0 = blockIdx.y * 128, N0 = blockIdx.x * 128;
    int wm = wave >> 1, wn = wave & 1;
    int lr = lane & 15;     // row within subtile
    int lq = lane >> 4;     // k-chunk (8 elems)

    float4v acc[4][4];
#pragma unroll
    for (int i = 0; i < 4; ++i)
#pragma unroll
        for (int j = 0; j < 4; ++j)
#pragma unroll
            for (int r = 0; r < 4; ++r) acc[i][j][r] = 0.f;

    const u16* aG0 = A  + (size_t)(M0 + (2*wave)    *16 + lr) * 512 + lq * 8;
    const u16* aG1 = A  + (size_t)(M0 + (2*wave + 1)*16 + lr) * 512 + lq * 8;
    const u16* bG0 = Bt + (size_t)(N0 + (2*wave)    *16 + lr) * 512 + lq * 8;
    const u16* bG1 = Bt + (size_t)(N0 + (2*wave + 1)*16 + lr) * 512 + lq * 8;
    u16* aL0 = &ldsA[(2*wave)     * 512];
    u16* aL1 = &ldsA[(2*wave + 1) * 512];
    u16* bL0 = &ldsB[(2*wave)     * 512];
    u16* bL1 = &ldsB[(2*wave + 1) * 512];

    for (int k0 = 0; k0 < 512; k0 += 32) {
        load_lds16(aG0 + k0, aL0);
        load_lds16(aG1 + k0, aL1);
        load_lds16(bG0 + k0, bL0);
        load_lds16(bG1 + k0, bL1);
        __syncthreads();
        short8 af[4], bfr[4];
#pragma unroll
        for (int i = 0; i < 4; ++i)
            af[i] = *(const short8*)&ldsA[(wm * 4 + i) * 512 + lane * 8];
#pragma unroll
        for (int j = 0; j < 4; ++j)
            bfr[j] = *(const short8*)&ldsB[(wn * 4 + j) * 512 + lane * 8];
#pragma unroll
        for (int i = 0; i < 4; ++i)
#pragma unroll
            for (int j = 0; j < 4; ++j)
                acc[i][j] = __builtin_amdgcn_mfma_f32_16x16x32_bf16(af[i], bfr[j], acc[i][j], 0, 0, 0);
        __syncthreads();
    }

    // C/D layout: col = lane&15, row = (lane>>4)*4 + r
#pragma unroll
    for (int j = 0; j < 4; ++j) {
        int col = N0 + (wn * 4 + j) * 16 + lr;
        float bc = bias[col];
#pragma unroll
        for (int i = 0; i < 4; ++i) {
            int row0 = M0 + (wm * 4 + i) * 16 + lq * 4;
#pragma unroll
            for (int r = 0; r < 4; ++r)
                C[(size_t)(row0 + r) * 512 + col] = f2bf(acc[i][j][r] + bc);
        }
    }
}

// ---------------- K2: row l2norm (bf16 in) + class scores + bf16 normalized out
__global__ __launch_bounds__(256) void normclass_kernel(
    const u16* __restrict__ xpr, const float* __restrict__ desc,
    u16* __restrict__ xpb, float* __restrict__ cls_out)
{
    __shared__ float sx[512];
    __shared__ float sred[8];
    __shared__ float sdots[32];
    int t = threadIdx.x;
    size_t row = blockIdx.x;
    const u16* xr = xpr + row * D_;
    u32 pk = *(const u32*)&xr[2 * t];
    float v0 = bf2f((u16)pk), v1 = bf2f((u16)(pk >> 16));
    float p = v0 * v0 + v1 * v1;
    int lane = t & 63, wave = t >> 6;
#pragma unroll
    for (int off = 32; off; off >>= 1) p += __shfl_down(p, off, 64);
    if (lane == 0) sred[wave] = p;
    __syncthreads();
    if (t == 0) {
        float s = sred[0] + sred[1] + sred[2] + sred[3];
        sred[4] = 1.0f / fmaxf(sqrtf(s), EPS_);
    }
    __syncthreads();
    float inv = sred[4];
    v0 *= inv; v1 *= inv;
    sx[2 * t] = v0; sx[2 * t + 1] = v1;
    *(u32*)&xpb[row * D_ + 2 * t] = (u32)f2bf(v0) | ((u32)f2bf(v1) << 16);
    __syncthreads();
    // 32 (c,k) dot products of 512; wave w handles 8 of them
#pragma unroll
    for (int q = 0; q < 8; ++q) {
        int pidx = wave * 8 + q;
        const float* dp = desc + (size_t)pidx * D_;
        float s = 0.f;
#pragma unroll
        for (int j = 0; j < D_; j += 64) s += sx[j + lane] * dp[j + lane];
#pragma unroll
        for (int off = 32; off; off >>= 1) s += __shfl_down(s, off, 64);
        if (lane == 0) sdots[pidx] = s;
    }
    __syncthreads();
    if (t < C_) {
        const float scale = 0.04419417382415922f;  // 512^-0.5
        float m = -1e30f;
        for (int k = 0; k < K_; ++k) m = fmaxf(m, sdots[t * K_ + k] * scale);
        float den = 0.f, num = 0.f;
        for (int k = 0; k < K_; ++k) {
            float e = expf(sdots[t * K_ + k] * scale - m);
            den += e; num += e * sdots[t * K_ + k];
        }
        cls_out[row * C_ + t] = num / den;
    }
}

// ---------------- K4: gated attention scalar per row (bf16 hvu) ----------------
__global__ __launch_bounds__(256) void gatedA_kernel(
    const u16* __restrict__ hvu, const float* __restrict__ w_attn,
    const float* __restrict__ b_attn, float* __restrict__ Araw)
{
    int wave = threadIdx.x >> 6, lane = threadIdx.x & 63;
    size_t row = (size_t)blockIdx.x * 4 + wave;
    const u16* hr = hvu + row * 512;
    float s = 0.f;
#pragma unroll
    for (int jj = 0; jj < 2; ++jj) {
        int h2 = jj * 128 + lane * 2;
        u32 pv = *(const u32*)&hr[h2];
        u32 pu = *(const u32*)&hr[256 + h2];
        float gv0 = tanhf(bf2f((u16)pv));
        float gv1 = tanhf(bf2f((u16)(pv >> 16)));
        float gu0 = 1.0f / (1.0f + expf(-bf2f((u16)pu)));
        float gu1 = 1.0f / (1.0f + expf(-bf2f((u16)(pu >> 16))));
        s += gv0 * gu0 * w_attn[h2] + gv1 * gu1 * w_attn[h2 + 1];
    }
#pragma unroll
    for (int off = 32; off; off >>= 1) s += __shfl_down(s, off, 64);
    if (lane == 0) Araw[row] = s + b_attn[0];
}

// ---------------- K5: softmax over N per batch ----------------
__global__ __launch_bounds__(256) void softmaxN_kernel(float* __restrict__ A)
{
    __shared__ float red[256];
    int t = threadIdx.x;
    float* Ab = A + (size_t)blockIdx.x * N_;
    float m = -1e30f;
    for (int i = t; i < N_; i += 256) m = fmaxf(m, Ab[i]);
    red[t] = m; __syncthreads();
    for (int s = 128; s; s >>= 1) { if (t < s) red[t] = fmaxf(red[t], red[t + s]); __syncthreads(); }
    m = red[0]; __syncthreads();
    float sum = 0.f;
    for (int i = t; i < N_; i += 256) { float e = expf(Ab[i] - m); Ab[i] = e; sum += e; }
    red[t] = sum; __syncthreads();
    for (int s = 128; s; s >>= 1) { if (t < s) red[t] += red[t + s]; __syncthreads(); }
    float inv = 1.0f / red[0];
    for (int i = t; i < N_; i += 256) Ab[i] *= inv;
}

// ---------------- K6: weighted pooling  slide[b] += sum A[n]*xp[n] ----------------
__global__ __launch_bounds__(256) void pool_kernel(
    const float* __restrict__ A, const u16* __restrict__ xpb, float* __restrict__ slide)
{
    int b = blockIdx.y;
    int t = threadIdx.x;
    size_t base = (size_t)b * N_ + (size_t)blockIdx.x * 64;
    float a0 = 0.f, a1 = 0.f;
    for (int r = 0; r < 64; ++r) {
        size_t row = base + r;
        float a = A[row];
        u32 pk = *(const u32*)&xpb[row * D_ + 2 * t];
        a0 += a * bf2f((u16)pk);
        a1 += a * bf2f((u16)(pk >> 16));
    }
    atomicAdd(&slide[b * D_ + 2 * t], a0);
    atomicAdd(&slide[b * D_ + 2 * t + 1], a1);
}

// ---------------- K7: finalize ----------------
__global__ __launch_bounds__(512) void finalize_kernel(
    const float* __restrict__ slide_s, const float* __restrict__ slide_l,
    const float* __restrict__ desc, float* __restrict__ out)
{
    __shared__ float txt[4][512];
    __shared__ float ssn[2][512];
    __shared__ float sln[2][512];
    __shared__ float red[512];
    __shared__ float lg[8];
    int t = threadIdx.x;

    auto reduceSum = [&](float v) -> float {
        red[t] = v; __syncthreads();
        for (int s = 256; s; s >>= 1) { if (t < s) red[t] += red[t + s]; __syncthreads(); }
        float r = red[0]; __syncthreads();
        return r;
    };

    for (int c = 0; c < 4; ++c) {
        float m = -1e30f;
        for (int k = 0; k < 8; ++k) m = fmaxf(m, desc[((size_t)c * 8 + k) * 512 + t]);
        float ss = reduceSum(m * m);
        txt[c][t] = m / fmaxf(sqrtf(ss), EPS_);
    }
    for (int b = 0; b < 2; ++b) {
        float v = slide_s[b * 512 + t];
        float ss = reduceSum(v * v);
        ssn[b][t] = v / fmaxf(sqrtf(ss), EPS_);
        v = slide_l[b * 512 + t];
        ss = reduceSum(v * v);
        sln[b][t] = v / fmaxf(sqrtf(ss), EPS_);
    }
    __syncthreads();
    for (int b = 0; b < 2; ++b)
        for (int c = 0; c < 4; ++c) {
            float v = ssn[b][t] * txt[c][t] + sln[b][t] * txt[c][t];
            float s = reduceSum(v);
            if (t == 0) lg[b * 4 + c] = s;
        }
    __syncthreads();
    if (t < 2) {
        int b = t;
        float m = -1e30f;
        for (int c = 0; c < 4; ++c) m = fmaxf(m, lg[b * 4 + c]);
        float e[4]; float den = 0.f;
        for (int c = 0; c < 4; ++c) { e[c] = expf(lg[b * 4 + c] - m); den += e[c]; }
        int am = 0; float bm = -1.f;
        for (int c = 0; c < 4; ++c) {
            float pcl = e[c] / den;
            out[b * 4 + c] = pcl;
            if (pcl > bm) { bm = pcl; am = c; }
        }
        out[8 + b] = (float)am;
    }
}

extern "C" void kernel_launch(void* const* d_in, const int* in_sizes, int n_in,
                              void* d_out, int out_size, void* d_ws, size_t ws_size,
                              hipStream_t stream) {
    const float* x_s    = (const float*)d_in[0];
    const float* x_l    = (const float*)d_in[2];
    const float* W_proj = (const float*)d_in[4];
    const float* b_proj = (const float*)d_in[5];
    const float* desc   = (const float*)d_in[6];
    const float* Wv     = (const float*)d_in[7];
    const float* bv     = (const float*)d_in[8];
    const float* Wu     = (const float*)d_in[9];
    const float* bu     = (const float*)d_in[10];
    const float* w_attn = (const float*)d_in[11];
    const float* b_attn = (const float*)d_in[12];
    float* out = (float*)d_out;

    // workspace layout (bytes):
    //  [0,32M)    xn bf16  (aliased: hvu bf16 after GEMM2 — xn dead by then)
    //  [32M,64M)  xpraw bf16 (GEMM1 out, pre-norm)
    //  [64M,96M)  xpb bf16   (normalized, for GEMM2 + pool)
    //  then WpT(512KB) WvuT(512KB) bvu(2KB) Araw(128KB) slide_s(4KB) slide_l(4KB)
    char* w = (char*)d_ws;
    u16* xn     = (u16*)w;                       // also hvu
    u16* xpraw  = (u16*)(w + (size_t)33554432);
    u16* xpb    = (u16*)(w + (size_t)67108864);
    u16* WpT    = (u16*)(w + (size_t)100663296);
    u16* WvuT   = (u16*)(w + (size_t)101187584);
    float* bvu  = (float*)(w + (size_t)101711872);
    float* Araw = (float*)(w + (size_t)101713920);
    float* slide_s = (float*)(w + (size_t)101845000 - 8);  // 101844992
    float* slide_l = slide_s + 1024;

    hipMemsetAsync(slide_s, 0, 8192, stream);
    prep_weights_kernel<<<1024, 256, 0, stream>>>(W_proj, Wv, Wu, bv, bu, WpT, WvuT, bvu);

    float* cls_s = out + 10;
    float* cls_l = out + 10 + (size_t)ROWS * C_;

    for (int s = 0; s < 2; ++s) {
        const float* x = s ? x_l : x_s;
        float* cls     = s ? cls_l : cls_s;
        float* slide   = s ? slide_l : slide_s;
        u16* hvu = xn;  // alias

        rownorm_cast_kernel<<<ROWS / 4, 256, 0, stream>>>(x, xn);
        gemm_bf16_kernel<<<dim3(4, ROWS / 128), 256, 0, stream>>>(xn, WpT, b_proj, xpraw);
        normclass_kernel<<<ROWS, 256, 0, stream>>>(xpraw, desc, xpb, cls);
        gemm_bf16_kernel<<<dim3(4, ROWS / 128), 256, 0, stream>>>(xpb, WvuT, bvu, hvu);
        gatedA_kernel<<<ROWS / 4, 256, 0, stream>>>(hvu, w_attn, b_attn, Araw);
        softmaxN_kernel<<<2, 256, 0, stream>>>(Araw);
        pool_kernel<<<dim3(N_ / 64, 2), 256, 0, stream>>>(Araw, xpb, slide);
    }
    finalize_kernel<<<1, 512, 0, stream>>>(slide_s, slide_l, desc, out);
}

// Round 3
// 502.640 us; speedup vs baseline: 2.8846x; 1.3695x over previous
//
#include <hip/hip_runtime.h>
#include <math.h>

#define B_ 2
#define N_ 16384
#define D_ 512
#define C_ 4
#define K_ 8
#define ROWS (B_*N_)   // 32768
#define EPS_ 1e-12f

typedef unsigned short u16;
typedef unsigned int u32;
using short8  = __attribute__((ext_vector_type(8))) short;
using float4v = __attribute__((ext_vector_type(4))) float;

__device__ __forceinline__ u16 f2bf(float f) {
    union { float f; u32 u; } v; v.f = f;
    u32 r = v.u + 0x7fffu + ((v.u >> 16) & 1u);
    return (u16)(r >> 16);
}
__device__ __forceinline__ u32 pack2(float a, float b) {
    return (u32)f2bf(a) | ((u32)f2bf(b) << 16);
}
__device__ __forceinline__ float bf2f(u16 h) {
    union { u32 u; float f; } v; v.u = ((u32)h) << 16;
    return v.f;
}
__device__ __forceinline__ void load_lds16(const u16* g, u16* l) {
    __builtin_amdgcn_global_load_lds(
        (const __attribute__((address_space(1))) u32*)g,
        (__attribute__((address_space(3))) u32*)l, 16, 0, 0);
}

// ---------------- P0: weight prep ----------------
// WpT[n][k] = Wp[k][n]  (bf16)
// WvuT interleaved: col n -> blk=n>>7, within=n&127, half=within>>6, h=blk*64+(within&63)
//   WvuT[n][k] = half ? Wu[k][h] : Wv[k][h];  bvu[n] likewise.
// descF: MFMA B-fragment order: descF[((kt*2+g)*64+l)*8+j] = desc[(g*16+(l&15))][kt*32+(l>>4)*8+j]
__global__ __launch_bounds__(256) void prep_weights_kernel(
    const float* __restrict__ Wp, const float* __restrict__ Wv, const float* __restrict__ Wu,
    const float* __restrict__ bv, const float* __restrict__ bu, const float* __restrict__ desc,
    u16* __restrict__ WpT, u16* __restrict__ WvuT, float* __restrict__ bvu,
    u16* __restrict__ descF)
{
    int idx = blockIdx.x * 256 + threadIdx.x;   // 0 .. 262143
    int n = idx >> 9, k = idx & 511;
    WpT[idx] = f2bf(Wp[k * 512 + n]);
    int blk = n >> 7, within = n & 127, half = within >> 6, h = blk * 64 + (within & 63);
    WvuT[idx] = f2bf(half ? Wu[k * 256 + h] : Wv[k * 256 + h]);
    if (idx < 512) {
        int b2 = idx >> 7, w2 = idx & 127, hf = w2 >> 6, h2 = b2 * 64 + (w2 & 63);
        bvu[idx] = hf ? bu[h2] : bv[h2];
    }
    if (idx < 16384) {
        int j = idx & 7, l = (idx >> 3) & 63, g = (idx >> 9) & 1, kt = idx >> 10;
        descF[idx] = f2bf(desc[(size_t)(g * 16 + (l & 15)) * 512 + kt * 32 + (l >> 4) * 8 + j]);
    }
}

// ---------------- K0: per-row L2-normalize x and cast to bf16 ----------------
__global__ __launch_bounds__(256) void rownorm_cast_kernel(
    const float* __restrict__ x, u16* __restrict__ xn)
{
    int wave = threadIdx.x >> 6, lane = threadIdx.x & 63;
    size_t row = (size_t)blockIdx.x * 4 + wave;
    const float* xr = x + row * D_;
    float4 a = *(const float4*)&xr[lane * 8];
    float4 b = *(const float4*)&xr[lane * 8 + 4];
    float s = a.x*a.x + a.y*a.y + a.z*a.z + a.w*a.w
            + b.x*b.x + b.y*b.y + b.z*b.z + b.w*b.w;
#pragma unroll
    for (int off = 32; off; off >>= 1) s += __shfl_xor(s, off, 64);
    float inv = 1.0f / fmaxf(sqrtf(s), EPS_);
    uint4 o;
    o.x = pack2(a.x * inv, a.y * inv);
    o.y = pack2(a.z * inv, a.w * inv);
    o.z = pack2(b.x * inv, b.y * inv);
    o.w = pack2(b.z * inv, b.w * inv);
    *(uint4*)&xn[row * D_ + lane * 8] = o;
}

// ---------------- K1: bf16 MFMA GEMM + bias, C bf16. 128x128 tile, BK=64.
// Swapped mfma operands: acc = mfma(bfr, af) => lane holds C[m = ..+lr][n = ..+lq*4+r]
__global__ __launch_bounds__(256) void gemm_bias_kernel(
    const u16* __restrict__ A, const u16* __restrict__ Bt,
    const float* __restrict__ bias, u16* __restrict__ C)
{
    __shared__ u16 ldsA[8192];
    __shared__ u16 ldsB[8192];
    int t = threadIdx.x;
    int wave = t >> 6, lane = t & 63;
    int lr = lane & 15, lq = lane >> 4;
    int M0 = blockIdx.y * 128, N0 = blockIdx.x * 128;
    int wm = wave >> 1, wn = wave & 1;

    float4v acc[4][4];
#pragma unroll
    for (int i = 0; i < 4; ++i)
#pragma unroll
        for (int j = 0; j < 4; ++j)
#pragma unroll
            for (int r = 0; r < 4; ++r) acc[i][j][r] = 0.f;

    const u16* aG[4]; const u16* bG[4]; u16* aL[4]; u16* bL[4];
#pragma unroll
    for (int s = 0; s < 4; ++s) {
        int u = wave * 4 + s, grp = u >> 1, ks = u & 1;
        int orow = grp * 16 + lr, ok = ks * 32 + lq * 8;
        aG[s] = A  + (size_t)(M0 + orow) * 512 + ok;
        bG[s] = Bt + (size_t)(N0 + orow) * 512 + ok;
        aL[s] = ldsA + u * 512;
        bL[s] = ldsB + u * 512;
    }

    for (int k0 = 0; k0 < 512; k0 += 64) {
#pragma unroll
        for (int s = 0; s < 4; ++s) load_lds16(aG[s] + k0, aL[s]);
#pragma unroll
        for (int s = 0; s < 4; ++s) load_lds16(bG[s] + k0, bL[s]);
        __syncthreads();
#pragma unroll
        for (int ks = 0; ks < 2; ++ks) {
            short8 af[4], bfr[4];
#pragma unroll
            for (int i = 0; i < 4; ++i)
                af[i] = *(const short8*)&ldsA[((wm * 4 + i) * 2 + ks) * 512 + lane * 8];
#pragma unroll
            for (int j = 0; j < 4; ++j)
                bfr[j] = *(const short8*)&ldsB[((wn * 4 + j) * 2 + ks) * 512 + lane * 8];
#pragma unroll
            for (int i = 0; i < 4; ++i)
#pragma unroll
                for (int j = 0; j < 4; ++j)
                    acc[i][j] = __builtin_amdgcn_mfma_f32_16x16x32_bf16(bfr[j], af[i], acc[i][j], 0, 0, 0);
        }
        __syncthreads();
    }

#pragma unroll
    for (int i = 0; i < 4; ++i) {
        int m = M0 + wm * 64 + i * 16 + lr;
        u16* crow = C + (size_t)m * 512;
#pragma unroll
        for (int j = 0; j < 4; ++j) {
            int nb = N0 + wn * 64 + j * 16 + lq * 4;
            float4 b4 = *(const float4*)&bias[nb];
            uint2 o;
            o.x = pack2(acc[i][j][0] + b4.x, acc[i][j][1] + b4.y);
            o.y = pack2(acc[i][j][2] + b4.z, acc[i][j][3] + b4.w);
            *(uint2*)&crow[nb] = o;
        }
    }
}

// ---------------- K3: GEMM2 with fused gated-attention epilogue ----------------
// A = xpraw (bf16, un-normalized), row-scale invn applied in epilogue.
// Bt = WvuT interleaved; per block col-range = [v h-range 64 | u same h-range].
// wn==0 waves: gv = tanh(acc*inv + bv)*w_attn -> LDS; wn==1: sigmoid(u) * gv -> atomicAdd Araw.
__global__ __launch_bounds__(256) void gemm_gate_kernel(
    const u16* __restrict__ A, const u16* __restrict__ Bt,
    const float* __restrict__ bias, const float* __restrict__ invn,
    const float* __restrict__ w_attn, float* __restrict__ Araw)
{
    __shared__ float smem[8320];            // 33280 B: staging (32KB) then gv[128][65]
    u16* ldsA = (u16*)smem;
    u16* ldsB = ldsA + 8192;
    float* gv = smem;
    int t = threadIdx.x;
    int wave = t >> 6, lane = t & 63;
    int lr = lane & 15, lq = lane >> 4;
    int M0 = blockIdx.y * 128, N0 = blockIdx.x * 128;
    int blk = blockIdx.x;
    int wm = wave >> 1, wn = wave & 1;

    float4v acc[4][4];
#pragma unroll
    for (int i = 0; i < 4; ++i)
#pragma unroll
        for (int j = 0; j < 4; ++j)
#pragma unroll
            for (int r = 0; r < 4; ++r) acc[i][j][r] = 0.f;

    const u16* aG[4]; const u16* bG[4]; u16* aL[4]; u16* bL[4];
#pragma unroll
    for (int s = 0; s < 4; ++s) {
        int u = wave * 4 + s, grp = u >> 1, ks = u & 1;
        int orow = grp * 16 + lr, ok = ks * 32 + lq * 8;
        aG[s] = A  + (size_t)(M0 + orow) * 512 + ok;
        bG[s] = Bt + (size_t)(N0 + orow) * 512 + ok;
        aL[s] = ldsA + u * 512;
        bL[s] = ldsB + u * 512;
    }

    for (int k0 = 0; k0 < 512; k0 += 64) {
#pragma unroll
        for (int s = 0; s < 4; ++s) load_lds16(aG[s] + k0, aL[s]);
#pragma unroll
        for (int s = 0; s < 4; ++s) load_lds16(bG[s] + k0, bL[s]);
        __syncthreads();
#pragma unroll
        for (int ks = 0; ks < 2; ++ks) {
            short8 af[4], bfr[4];
#pragma unroll
            for (int i = 0; i < 4; ++i)
                af[i] = *(const short8*)&ldsA[((wm * 4 + i) * 2 + ks) * 512 + lane * 8];
#pragma unroll
            for (int j = 0; j < 4; ++j)
                bfr[j] = *(const short8*)&ldsB[((wn * 4 + j) * 2 + ks) * 512 + lane * 8];
#pragma unroll
            for (int i = 0; i < 4; ++i)
#pragma unroll
                for (int j = 0; j < 4; ++j)
                    acc[i][j] = __builtin_amdgcn_mfma_f32_16x16x32_bf16(bfr[j], af[i], acc[i][j], 0, 0, 0);
        }
        __syncthreads();
    }

    if (wn == 0) {   // v-half: cols N0..N0+63
#pragma unroll
        for (int i = 0; i < 4; ++i) {
            int mloc = wm * 64 + i * 16 + lr;
            float iv = invn[M0 + mloc];
#pragma unroll
            for (int j = 0; j < 4; ++j) {
#pragma unroll
                for (int r = 0; r < 4; ++r) {
                    int hh = j * 16 + lq * 4 + r;
                    int h = blk * 64 + hh;
                    float val = acc[i][j][r] * iv + bias[N0 + hh];
                    gv[mloc * 65 + hh] = tanhf(val) * w_attn[h];
                }
            }
        }
    }
    __syncthreads();
    if (wn == 1) {   // u-half: cols N0+64..N0+127
#pragma unroll
        for (int i = 0; i < 4; ++i) {
            int mloc = wm * 64 + i * 16 + lr;
            float iv = invn[M0 + mloc];
            float part = 0.f;
#pragma unroll
            for (int j = 0; j < 4; ++j) {
#pragma unroll
                for (int r = 0; r < 4; ++r) {
                    int hh = j * 16 + lq * 4 + r;
                    float val = acc[i][j][r] * iv + bias[N0 + 64 + hh];
                    float su = 1.0f / (1.0f + expf(-val));
                    part += gv[mloc * 65 + hh] * su;
                }
            }
            part += __shfl_xor(part, 16, 64);
            part += __shfl_xor(part, 32, 64);
            if (lq == 0) atomicAdd(&Araw[M0 + mloc], part);
        }
    }
}

// ---------------- K2: MFMA class scores + row inv-norm (Gram-diag trick) ----------------
__global__ __launch_bounds__(256) void classscore_kernel(
    const u16* __restrict__ xpraw, const u16* __restrict__ descF,
    float* __restrict__ invn, float* __restrict__ cls_out)
{
    __shared__ u16 descL[16384];   // 32KB: 16 k-tiles x 2 groups, fragment order
    __shared__ float sInv[4][16];
    int t = threadIdx.x, wave = t >> 6, lane = t & 63;
    int lr = lane & 15, lq = lane >> 4;
#pragma unroll
    for (int s = 0; s < 8; ++s) {
        int u = wave * 8 + s;
        load_lds16(descF + u * 512 + lane * 8, descL + u * 512);
    }
    int base0 = blockIdx.x * 64 + wave * 16;
    short8 af[16];
#pragma unroll
    for (int kt = 0; kt < 16; ++kt)
        af[kt] = *(const short8*)(xpraw + (size_t)(base0 + lr) * 512 + kt * 32 + lq * 8);
    __syncthreads();

    float4v accS0 = {0.f, 0.f, 0.f, 0.f};
    float4v accS1 = {0.f, 0.f, 0.f, 0.f};
    float4v accG  = {0.f, 0.f, 0.f, 0.f};
#pragma unroll
    for (int kt = 0; kt < 16; ++kt) {
        short8 d0 = *(const short8*)&descL[(kt * 2 + 0) * 512 + lane * 8];
        short8 d1 = *(const short8*)&descL[(kt * 2 + 1) * 512 + lane * 8];
        accS0 = __builtin_amdgcn_mfma_f32_16x16x32_bf16(af[kt], d0, accS0, 0, 0, 0);
        accS1 = __builtin_amdgcn_mfma_f32_16x16x32_bf16(af[kt], d1, accS1, 0, 0, 0);
        accG  = __builtin_amdgcn_mfma_f32_16x16x32_bf16(af[kt], af[kt], accG, 0, 0, 0);
    }
    // diag of Gram = row norm^2 ; lane holds G[p=lq*4+r][q=lr] -> diag where lr==lq*4+r
#pragma unroll
    for (int r = 0; r < 4; ++r) {
        if (lr == lq * 4 + r) {
            float iv = 1.0f / fmaxf(sqrtf(accG[r]), EPS_);
            sInv[wave][lq * 4 + r] = iv;
            invn[base0 + lq * 4 + r] = iv;
        }
    }
    __syncthreads();
    const float scale = 0.04419417382415922f;   // 512^-0.5
#pragma unroll
    for (int r = 0; r < 4; ++r) {
        int row = base0 + lq * 4 + r;
        float iv = sInv[wave][lq * 4 + r];
        float sv0 = accS0[r] * iv, sv1 = accS1[r] * iv;
#pragma unroll
        for (int g = 0; g < 2; ++g) {
            float s = g ? sv1 : sv0;
            float ts = s * scale;
            float mx = ts;
            mx = fmaxf(mx, __shfl_xor(mx, 1, 64));
            mx = fmaxf(mx, __shfl_xor(mx, 2, 64));
            mx = fmaxf(mx, __shfl_xor(mx, 4, 64));
            float e = expf(ts - mx);
            float num = e * s, den = e;
            num += __shfl_xor(num, 1, 64); den += __shfl_xor(den, 1, 64);
            num += __shfl_xor(num, 2, 64); den += __shfl_xor(den, 2, 64);
            num += __shfl_xor(num, 4, 64); den += __shfl_xor(den, 4, 64);
            if ((lr & 7) == 0) {
                int c = g * 2 + ((lr >> 3) & 1);
                cls_out[(size_t)row * 4 + c] = num / den;
            }
        }
    }
}

// ---------------- K5: softmax over N per batch (b_attn dropped: shift-invariant) ------
__global__ __launch_bounds__(256) void softmaxN_kernel(float* __restrict__ A)
{
    __shared__ float red[256];
    int t = threadIdx.x;
    float* Ab = A + (size_t)blockIdx.x * N_;
    float m = -1e30f;
    for (int i = t; i < N_; i += 256) m = fmaxf(m, Ab[i]);
    red[t] = m; __syncthreads();
    for (int s = 128; s; s >>= 1) { if (t < s) red[t] = fmaxf(red[t], red[t + s]); __syncthreads(); }
    m = red[0]; __syncthreads();
    float sum = 0.f;
    for (int i = t; i < N_; i += 256) { float e = expf(Ab[i] - m); Ab[i] = e; sum += e; }
    red[t] = sum; __syncthreads();
    for (int s = 128; s; s >>= 1) { if (t < s) red[t] += red[t + s]; __syncthreads(); }
    float inv = 1.0f / red[0];
    for (int i = t; i < N_; i += 256) Ab[i] *= inv;
}

// ---------------- K6: weighted pooling with on-the-fly row scale ----------------
__global__ __launch_bounds__(256) void pool_kernel(
    const float* __restrict__ Asoft, const float* __restrict__ invn,
    const u16* __restrict__ xpraw, float* __restrict__ slide)
{
    int b = blockIdx.y;
    int t = threadIdx.x;
    size_t base = (size_t)b * N_ + (size_t)blockIdx.x * 64;
    float a0 = 0.f, a1 = 0.f;
    for (int r = 0; r < 64; ++r) {
        size_t row = base + r;
        float a = Asoft[row] * invn[row];
        u32 pk = *(const u32*)&xpraw[row * D_ + 2 * t];
        a0 += a * bf2f((u16)pk);
        a1 += a * bf2f((u16)(pk >> 16));
    }
    atomicAdd(&slide[b * D_ + 2 * t], a0);
    atomicAdd(&slide[b * D_ + 2 * t + 1], a1);
}

// ---------------- K7: finalize ----------------
__global__ __launch_bounds__(512) void finalize_kernel(
    const float* __restrict__ slide_s, const float* __restrict__ slide_l,
    const float* __restrict__ desc, float* __restrict__ out)
{
    __shared__ float txt[4][512];
    __shared__ float ssn[2][512];
    __shared__ float sln[2][512];
    __shared__ float red[512];
    __shared__ float lg[8];
    int t = threadIdx.x;

    auto reduceSum = [&](float v) -> float {
        red[t] = v; __syncthreads();
        for (int s = 256; s; s >>= 1) { if (t < s) red[t] += red[t + s]; __syncthreads(); }
        float r = red[0]; __syncthreads();
        return r;
    };

    for (int c = 0; c < 4; ++c) {
        float m = -1e30f;
        for (int k = 0; k < 8; ++k) m = fmaxf(m, desc[((size_t)c * 8 + k) * 512 + t]);
        float ss = reduceSum(m * m);
        txt[c][t] = m / fmaxf(sqrtf(ss), EPS_);
    }
    for (int b = 0; b < 2; ++b) {
        float v = slide_s[b * 512 + t];
        float ss = reduceSum(v * v);
        ssn[b][t] = v / fmaxf(sqrtf(ss), EPS_);
        v = slide_l[b * 512 + t];
        ss = reduceSum(v * v);
        sln[b][t] = v / fmaxf(sqrtf(ss), EPS_);
    }
    __syncthreads();
    for (int b = 0; b < 2; ++b)
        for (int c = 0; c < 4; ++c) {
            float v = ssn[b][t] * txt[c][t] + sln[b][t] * txt[c][t];
            float s = reduceSum(v);
            if (t == 0) lg[b * 4 + c] = s;
        }
    __syncthreads();
    if (t < 2) {
        int b = t;
        float m = -1e30f;
        for (int c = 0; c < 4; ++c) m = fmaxf(m, lg[b * 4 + c]);
        float e[4]; float den = 0.f;
        for (int c = 0; c < 4; ++c) { e[c] = expf(lg[b * 4 + c] - m); den += e[c]; }
        int am = 0; float bm = -1.f;
        for (int c = 0; c < 4; ++c) {
            float pcl = e[c] / den;
            out[b * 4 + c] = pcl;
            if (pcl > bm) { bm = pcl; am = c; }
        }
        out[8 + b] = (float)am;
    }
}

extern "C" void kernel_launch(void* const* d_in, const int* in_sizes, int n_in,
                              void* d_out, int out_size, void* d_ws, size_t ws_size,
                              hipStream_t stream) {
    const float* x_s    = (const float*)d_in[0];
    const float* x_l    = (const float*)d_in[2];
    const float* W_proj = (const float*)d_in[4];
    const float* b_proj = (const float*)d_in[5];
    const float* desc   = (const float*)d_in[6];
    const float* Wv     = (const float*)d_in[7];
    const float* bv     = (const float*)d_in[8];
    const float* Wu     = (const float*)d_in[9];
    const float* bu     = (const float*)d_in[10];
    const float* w_attn = (const float*)d_in[11];
    float* out = (float*)d_out;

    // workspace layout (bytes):
    //  0        : xn    bf16 [32768x512]  (33554432)
    //  33554432 : xpraw bf16 [32768x512]  (33554432)
    //  67108864 : WpT   bf16 [512x512]    (524288)
    //  67633152 : WvuT  bf16 [512x512]    (524288, interleaved)
    //  68157440 : descF bf16 fragment     (32768)
    //  68190208 : bvu   f32 [512]         (2048, interleaved)
    //  68192256 : invn  f32 [32768]       (131072)
    //  68323328 : slide_s f32 [2x512]     (4096)
    //  68327424 : slide_l f32 [2x512]     (4096)
    //  68331520 : Araw0 f32 [32768]       (131072)
    //  68462592 : Araw1 f32 [32768]       (131072)
    char* w = (char*)d_ws;
    u16* xn      = (u16*)w;
    u16* xpraw   = (u16*)(w + 33554432);
    u16* WpT     = (u16*)(w + 67108864);
    u16* WvuT    = (u16*)(w + 67633152);
    u16* descF   = (u16*)(w + 68157440);
    float* bvu   = (float*)(w + 68190208);
    float* invn  = (float*)(w + 68192256);
    float* slide_s = (float*)(w + 68323328);
    float* slide_l = (float*)(w + 68327424);
    float* Araw0 = (float*)(w + 68331520);

    // zero slides + Araw (contiguous 270336 B)
    hipMemsetAsync(slide_s, 0, 270336, stream);
    prep_weights_kernel<<<1024, 256, 0, stream>>>(W_proj, Wv, Wu, bv, bu, desc,
                                                  WpT, WvuT, bvu, descF);

    float* cls_s = out + 10;
    float* cls_l = out + 10 + (size_t)ROWS * C_;

    for (int s = 0; s < 2; ++s) {
        const float* x = s ? x_l : x_s;
        float* cls     = s ? cls_l : cls_s;
        float* slide   = s ? slide_l : slide_s;
        float* Araw    = Araw0 + (size_t)s * ROWS;

        rownorm_cast_kernel<<<ROWS / 4, 256, 0, stream>>>(x, xn);
        gemm_bias_kernel<<<dim3(4, ROWS / 128), 256, 0, stream>>>(xn, WpT, b_proj, xpraw);
        classscore_kernel<<<ROWS / 64, 256, 0, stream>>>(xpraw, descF, invn, cls);
        gemm_gate_kernel<<<dim3(4, ROWS / 128), 256, 0, stream>>>(xpraw, WvuT, bvu, invn, w_attn, Araw);
        softmaxN_kernel<<<2, 256, 0, stream>>>(Araw);
        pool_kernel<<<dim3(N_ / 64, 2), 256, 0, stream>>>(Araw, invn, xpraw, slide);
    }
    finalize_kernel<<<1, 512, 0, stream>>>(slide_s, slide_l, desc, out);
}